// Round 17
// baseline (343.082 us; speedup 1.0000x reference)
//
#include <hip/hip_runtime.h>
#include <hip/hip_bf16.h>
#include <math.h>

#define NT 512

typedef __attribute__((ext_vector_type(8))) short short8v;
typedef __attribute__((ext_vector_type(4))) short short4v;
typedef __attribute__((ext_vector_type(4))) float f32x4;
typedef __attribute__((ext_vector_type(2))) unsigned uint2v;
typedef __attribute__((ext_vector_type(4))) unsigned uint4v;

__device__ __forceinline__ unsigned short f2bf(float x) {   // prep kernel only
    unsigned u = __float_as_uint(x);
    unsigned r = ((u >> 16) & 1u) + 0x7FFFu;
    return (unsigned short)((u + r) >> 16);
}
__device__ __forceinline__ unsigned pk2(float a, float b) {
    __hip_bfloat162 h = __float22bfloat162_rn(make_float2(a, b));
    unsigned r;
    __builtin_memcpy(&r, &h, sizeof(r));
    return r;
}
__device__ __forceinline__ short bf1(float a) {
    __hip_bfloat16 h = __float2bfloat16(a);
    short r;
    __builtin_memcpy(&r, &h, sizeof(r));
    return r;
}
__device__ __forceinline__ float exp2fast(float x) {
#if __has_builtin(__builtin_amdgcn_exp2f)
    return __builtin_amdgcn_exp2f(x);
#else
    return exp2f(x);
#endif
}
__device__ __forceinline__ float rcpfast(float x) {
#if __has_builtin(__builtin_amdgcn_rcpf)
    return __builtin_amdgcn_rcpf(x);
#else
    return 1.0f / x;
#endif
}
// tanh-form gelu via exp2 + rcp (|err| vs erf-gelu ~3e-3, inside tolerance)
__device__ __forceinline__ float gelu_f(float x) {
    float x3 = x * x * x;
    float e = exp2fast(-2.3022079f * x - 0.1029432f * x3);
    return x * rcpfast(1.0f + e);
}
__device__ __forceinline__ f32x4 mfma32(short8v a, short8v b, f32x4 c) {
    return __builtin_amdgcn_mfma_f32_16x16x32_bf16(a, b, c, 0, 0, 0);
}
__device__ __forceinline__ f32x4 mfma16(short4v a, short4v b, f32x4 c) {
    return __builtin_amdgcn_mfma_f32_16x16x16bf16_1k(a, b, c, 0, 0, 0);
}

template<int M>
__device__ __forceinline__ void stats_tree(const f32x4* v, float& s1o, float& s2o) {
    float a[M], b[M];
    #pragma unroll
    for (int i = 0; i < M; ++i) {
        a[i] = (v[i][0] + v[i][1]) + (v[i][2] + v[i][3]);
        float q0 = v[i][0] * v[i][0], q1 = v[i][1] * v[i][1];
        float q2 = v[i][2] * v[i][2], q3 = v[i][3] * v[i][3];
        b[i] = (q0 + q1) + (q2 + q3);
    }
    #pragma unroll
    for (int s = 1; s < M; s *= 2)
        #pragma unroll
        for (int i = 0; i + s < M; i += 2 * s) { a[i] += a[i + s]; b[i] += b[i + s]; }
    s1o = a[0]; s2o = b[0];
}

// ws layout (bf16 shorts): wqkvT[L][192][64] @0 ; woT[L][64][64] @49152 ;
//                          w1T[L][16][64] @65536 (rows j>=8 zero) ; w2T[L][64][8] @69632
#define WS_WO 49152
#define WS_W1 65536
#define WS_W2 69632
#define WS_TOT 71680

__global__ __launch_bounds__(256) void prep_kernel(
    const float* __restrict__ w_qkv, const float* __restrict__ w_o,
    const float* __restrict__ w1, const float* __restrict__ w2,
    short* __restrict__ ws)
{
    int idx = blockIdx.x * 256 + threadIdx.x;
    if (idx < WS_WO) {
        int l = idx / 12288, r = idx % 12288, c = r >> 6, d = r & 63;
        ws[idx] = (short)f2bf(w_qkv[l * 12288 + d * 192 + c]);
    } else if (idx < WS_W1) {
        int k = idx - WS_WO; int l = k / 4096, r = k % 4096, c = r >> 6, d = r & 63;
        ws[idx] = (short)f2bf(w_o[l * 4096 + d * 64 + c]);
    } else if (idx < WS_W2) {
        int k = idx - WS_W1; int l = k / 1024, r = k % 1024, j = r >> 6, d = r & 63;
        ws[idx] = (j < 8) ? (short)f2bf(w1[l * 512 + d * 8 + j]) : (short)0;
    } else if (idx < WS_TOT) {
        int k = idx - WS_W2; int l = k / 512, r = k % 512, c = r >> 3, j = r & 7;
        ws[idx] = (short)f2bf(w2[l * 512 + j * 64 + c]);
    }
}

// LDS (51.2 KB -> 3 blocks/CU): xs fp32 [81][68] (full 9x9 grid, ring-indexed);
// ybuf bf16 [96][72] = LN1 input; qbf bf16 [96][72] = attn-out; hb bf16 [96][8].
// Fully fused QKV+attention: wave h computes q (JIT per tile), k, v in registers
// from ybuf; 2 barriers/layer total.
template<int N, int P, int L, bool FIRST, bool LAST>
__device__ __forceinline__ void layer_fn(
    float* __restrict__ xs, short* __restrict__ ybuf, short* __restrict__ qbf,
    short* __restrict__ hb, const short* __restrict__ ws,
    const float* __restrict__ b_qkv, const float* __restrict__ b_o,
    const float* __restrict__ ln1_g, const float* __restrict__ ln1_b,
    const float* __restrict__ ln2_g, const float* __restrict__ ln2_b,
    const float* __restrict__ b1,    const float* __restrict__ b2,
    float* __restrict__ out, int b, int t)
{
    constexpr int Mt = (N + 15) / 16;
    constexpr float SCL2E = 0.51010905835f;   // (HEAD_DIM/HEADS)^-0.5 * log2(e)
    const int wv = t >> 6, l = t & 63, lr = l & 15, lq = l >> 4;
    short8v zero8 = {};
    f32x4 zero4 = {0.f, 0.f, 0.f, 0.f};

    // ---- phase A (first layer only): LN1 -> ybuf. 4 lanes per token ----
    if (FIRST) {
        if (t < 64 * Mt) {
            const int token = t >> 2, part = t & 3, d0 = part * 16;
            short* yrow = ybuf + token * 72 + d0;
            if (token < N) {
                const int row = (token / P + L) * 9 + token % P + L;
                const float* xr = xs + row * 68 + d0;
                f32x4 v[4];
                #pragma unroll
                for (int k = 0; k < 4; ++k) v[k] = *(const f32x4*)(xr + 4 * k);
                float s1, s2;
                stats_tree<4>(v, s1, s2);
                s1 += __shfl_xor(s1, 1); s2 += __shfl_xor(s2, 1);
                s1 += __shfl_xor(s1, 2); s2 += __shfl_xor(s2, 2);
                const float m = s1 * 0.015625f;
                const float r = rsqrtf(s2 * 0.015625f - m * m + 1e-5f);
                uint4v w0, w1v;
                #pragma unroll
                for (int k = 0; k < 4; ++k) {
                    f32x4 g  = *(const f32x4*)&ln1_g[L * 64 + d0 + 4 * k];
                    f32x4 bb = *(const f32x4*)&ln1_b[L * 64 + d0 + 4 * k];
                    unsigned p0 = pk2((v[k][0]-m)*r*g[0]+bb[0], (v[k][1]-m)*r*g[1]+bb[1]);
                    unsigned p1 = pk2((v[k][2]-m)*r*g[2]+bb[2], (v[k][3]-m)*r*g[3]+bb[3]);
                    if (k == 0) { w0.x = p0; w0.y = p1; }
                    else if (k == 1) { w0.z = p0; w0.w = p1; }
                    else if (k == 2) { w1v.x = p0; w1v.y = p1; }
                    else { w1v.z = p0; w1v.w = p1; }
                }
                *(uint4v*)yrow = w0;
                *(uint4v*)(yrow + 8) = w1v;
            } else {
                uint4v z = {};
                *(uint4v*)yrow = z;
                *(uint4v*)(yrow + 8) = z;
            }
        }
        __syncthreads();
    }

    // ---- phase C: fully fused qkv + attention. wave = head h.
    //      k/v in registers (combined pass, shared y loads); q computed JIT per
    //      query tile with the SAME srcl redistribution as k (identical layout
    //      derivation); attn-out written to qbf's own-head columns. ----
    {
        const int h = wv, a = h & 1, ct = h >> 1;
        const int srcl = lr + 32 * a + (l & 16);
        const short* wqL = ws + L * 12288;

        // hoisted weight fragments + biases for this wave's 16-channel group
        const short* wqr = &wqL[(16 * ct + lr) * 64 + lq * 8];
        short8v wq0 = *(const short8v*)wqr, wq1 = *(const short8v*)(wqr + 32);
        f32x4 qb = *(const f32x4*)&b_qkv[L * 192 + 16 * ct + lq * 4];
        const short* wkr = &wqL[(64 + 16 * ct + lr) * 64 + lq * 8];
        short8v wk0 = *(const short8v*)wkr, wk1 = *(const short8v*)(wkr + 32);
        f32x4 kb = *(const f32x4*)&b_qkv[L * 192 + 64 + 16 * ct + lq * 4];
        const short* wvr = &wqL[(128 + 16 * ct + lr) * 64 + lq * 8];
        short8v wv0 = *(const short8v*)wvr, wv1 = *(const short8v*)(wvr + 32);
        const float vbi = b_qkv[L * 192 + 128 + 16 * ct + lr];

        // combined k/v pass (one y-row load per tile)
        short4v vf[Mt];
        uint2v kf[Mt];
        #pragma unroll
        for (int mt = 0; mt < Mt; ++mt) {
            const short* yr = &ybuf[(16 * mt + lr) * 72 + lq * 8];
            short8v y0 = *(const short8v*)yr, y1 = *(const short8v*)(yr + 32);
            // v: unswapped GEMM -> D fragment == PV A-operand fragment
            f32x4 av = mfma32(y0, wv0, zero4);
            av = mfma32(y1, wv1, av);
            uint2v uv;
            uv.x = pk2(av[0] + vbi, av[1] + vbi);
            uv.y = pk2(av[2] + vbi, av[3] + vbi);
            vf[mt] = __builtin_bit_cast(short4v, uv);
            // k: swapped GEMM + redistribution (2 shfl) -> scores A fragment
            f32x4 ak = mfma32(wk0, y0, zero4);
            ak = mfma32(wk1, y1, ak);
            unsigned ka = pk2(ak[0] + kb[0], ak[1] + kb[1]);
            unsigned kc = pk2(ak[2] + kb[2], ak[3] + kb[3]);
            unsigned u0 = (unsigned)__shfl((int)ka, srcl);
            unsigned u1 = (unsigned)__shfl((int)kc, srcl);
            uint2v kv2; kv2.x = (l < 32) ? u0 : 0u; kv2.y = (l < 32) ? u1 : 0u;
            kf[mt] = kv2;
        }
        // scores + softmax + PV per query tile; q computed just-in-time
        for (int mt = 0; mt < Mt; ++mt) {
            const short* yr = &ybuf[(16 * mt + lr) * 72 + lq * 8];
            short8v y0 = *(const short8v*)yr, y1 = *(const short8v*)(yr + 32);
            f32x4 aq = mfma32(wq0, y0, zero4);
            aq = mfma32(wq1, y1, aq);
            unsigned qa = pk2((aq[0] + qb[0]) * SCL2E, (aq[1] + qb[1]) * SCL2E);
            unsigned qc = pk2((aq[2] + qb[2]) * SCL2E, (aq[3] + qb[3]) * SCL2E);
            unsigned uq0 = (unsigned)__shfl((int)qa, srcl);
            unsigned uq1 = (unsigned)__shfl((int)qc, srcl);
            uint2v qw; qw.x = (l < 32) ? uq0 : 0u; qw.y = (l < 32) ? uq1 : 0u;
            short4v qv = __builtin_bit_cast(short4v, qw);

            float psA = 0.f, psB = 0.f;
            f32x4 po0 = zero4, po1 = zero4;
            #pragma unroll
            for (int jt = 0; jt < Mt; ++jt) {
                f32x4 s = mfma16(__builtin_bit_cast(short4v, kf[jt]), qv, zero4);
                float e0 = exp2fast(s[0]), e1 = exp2fast(s[1]);
                float e2 = exp2fast(s[2]), e3 = exp2fast(s[3]);
                if (jt == Mt - 1) {   // only the last tile contains pad keys
                    const int j0 = 16 * jt + lq * 4;
                    e0 = (j0 + 0 < N) ? e0 : 0.f;
                    e1 = (j0 + 1 < N) ? e1 : 0.f;
                    e2 = (j0 + 2 < N) ? e2 : 0.f;
                    e3 = (j0 + 3 < N) ? e3 : 0.f;
                }
                psA += e0 + e1; psB += e2 + e3;
                uint2v pv; pv.x = pk2(e0, e1); pv.y = pk2(e2, e3);
                short4v bv = __builtin_bit_cast(short4v, pv);
                if (jt & 1) po1 = mfma16(vf[jt], bv, po1);
                else        po0 = mfma16(vf[jt], bv, po0);
            }
            float psum = psA + psB;
            float den = psum + __shfl_xor(psum, 16);
            den += __shfl_xor(den, 32);
            const float dinv = rcpfast(den);
            if ((lq >> 1) == a) {
                const int i = 16 * mt + lr;
                if (i < N) {
                    unsigned q0 = pk2((po0[0] + po1[0]) * dinv, (po0[1] + po1[1]) * dinv);
                    unsigned q1 = pk2((po0[2] + po1[2]) * dinv, (po0[3] + po1[3]) * dinv);
                    unsigned* dst = (unsigned*)&qbf[i * 72 + 8 * h + (lq & 1) * 4];
                    dst[0] = q0; dst[1] = q1;
                }
            }
        }
    }
    __syncthreads();

    // ---- phase D (fused, wave-local): w_o + residual + LN2 + MLP + residual
    //      + LN1-of-next-layer written into ybuf. ----
    {
        if (wv < Mt) {
            const int mt = wv;
            const int i = 16 * mt + lr;          // token (this layer)
            const bool iok = (i < N);
            const int xrow = iok ? (i / P + L) * 9 + (i % P) + L : 0;
            float* xp = xs + xrow * 68;
            const short* yr = &qbf[i * 72 + lq * 8];   // attn-out
            short8v y0 = *(const short8v*)yr;
            short8v y1 = *(const short8v*)(yr + 32);
            const short* woL = ws + WS_WO + L * 4096;
            f32x4 xv[4];
            #pragma unroll
            for (int ctp = 0; ctp < 4; ++ctp) {
                const short* wr = &woL[(16 * ctp + lr) * 64 + lq * 8];
                f32x4 acc = mfma32(*(const short8v*)wr, y0, zero4);
                acc = mfma32(*(const short8v*)(wr + 32), y1, acc);
                f32x4 bo = *(const f32x4*)&b_o[L * 64 + 16 * ctp + 4 * lq];
                f32x4 xc = zero4;
                if (iok) xc = *(const f32x4*)(xp + 16 * ctp + 4 * lq);
                #pragma unroll
                for (int rg = 0; rg < 4; ++rg) xc[rg] += acc[rg] + bo[rg];
                xv[ctp] = xc;
            }
            float s1, s2;
            stats_tree<4>(xv, s1, s2);
            s1 += __shfl_xor(s1, 16); s2 += __shfl_xor(s2, 16);
            s1 += __shfl_xor(s1, 32); s2 += __shfl_xor(s2, 32);
            const float m = s1 * 0.015625f;
            const float r = rsqrtf(s2 * 0.015625f - m * m + 1e-5f);
            unsigned* abw = (unsigned*)&qbf[i * 72];
            #pragma unroll
            for (int ctp = 0; ctp < 4; ++ctp) {
                f32x4 g  = *(const f32x4*)&ln2_g[L * 64 + 16 * ctp + 4 * lq];
                f32x4 bb = *(const f32x4*)&ln2_b[L * 64 + 16 * ctp + 4 * lq];
                abw[8 * ctp + 2 * lq]     = pk2((xv[ctp][0]-m)*r*g[0]+bb[0],
                                                (xv[ctp][1]-m)*r*g[1]+bb[1]);
                abw[8 * ctp + 2 * lq + 1] = pk2((xv[ctp][2]-m)*r*g[2]+bb[2],
                                                (xv[ctp][3]-m)*r*g[3]+bb[3]);
            }
            // MLP up (same-wave LDS round-trip, matched unsigned types)
            uint4v ua0 = *(const uint4v*)(abw + 4 * lq);
            uint4v ua1 = *(const uint4v*)(abw + 16 + 4 * lq);
            const short* w1L = ws + WS_W1 + L * 1024;
            short8v a10 = __builtin_bit_cast(short8v, ua0);
            short8v a11 = __builtin_bit_cast(short8v, ua1);
            short8v b10 = *(const short8v*)&w1L[lr * 64 + lq * 8];
            short8v b11 = *(const short8v*)&w1L[lr * 64 + lq * 8 + 32];
            f32x4 hA = mfma32(a10, b10, zero4);
            hA = mfma32(a11, b11, hA);
            if (lr < 8) {
                const float bg = b1[L * 8 + lr];
                #pragma unroll
                for (int rg = 0; rg < 4; ++rg)
                    hb[(16 * mt + 4 * lq + rg) * 8 + lr] = bf1(gelu_f(hA[rg] + bg));
            }
            // MLP down, swapped orientation: D[ch 16ctp+4lq+rg][tok lr]
            short8v hbf = (lq == 0) ? *(const short8v*)&hb[(16 * mt + lr) * 8] : zero8;
            const short* w2L = ws + WS_W2 + L * 512;
            f32x4 xf[4];
            #pragma unroll
            for (int ctp = 0; ctp < 4; ++ctp) {
                short8v a2 = (lq == 0) ? *(const short8v*)&w2L[(16 * ctp + lr) * 8] : zero8;
                f32x4 dacc = mfma32(a2, hbf, zero4);
                f32x4 b2v = *(const f32x4*)&b2[L * 64 + 16 * ctp + 4 * lq];
                #pragma unroll
                for (int rg = 0; rg < 4; ++rg) xf[ctp][rg] = xv[ctp][rg] + dacc[rg] + b2v[rg];
                if (iok) *(f32x4*)(xp + 16 * ctp + 4 * lq) = xf[ctp];
            }
            if (!LAST) {
                // LN1 of the next layer, straight from registers -> ybuf
                float t1, t2;
                stats_tree<4>(xf, t1, t2);
                t1 += __shfl_xor(t1, 16); t2 += __shfl_xor(t2, 16);
                t1 += __shfl_xor(t1, 32); t2 += __shfl_xor(t2, 32);
                const float mn = t1 * 0.015625f;
                const float rn = rsqrtf(t2 * 0.015625f - mn * mn + 1e-5f);
                const int r_ = i / P, c_ = i % P;
                const bool vok = iok && r_ >= 1 && r_ <= P - 2 && c_ >= 1 && c_ <= P - 2;
                if (vok) {
                    const int j = (r_ - 1) * (P - 2) + (c_ - 1);
                    unsigned* yw = (unsigned*)&ybuf[j * 72];
                    #pragma unroll
                    for (int ctp = 0; ctp < 4; ++ctp) {
                        f32x4 g  = *(const f32x4*)&ln1_g[(L + 1) * 64 + 16 * ctp + 4 * lq];
                        f32x4 bb = *(const f32x4*)&ln1_b[(L + 1) * 64 + 16 * ctp + 4 * lq];
                        yw[8 * ctp + 2 * lq]     = pk2((xf[ctp][0]-mn)*rn*g[0]+bb[0],
                                                       (xf[ctp][1]-mn)*rn*g[1]+bb[1]);
                        yw[8 * ctp + 2 * lq + 1] = pk2((xf[ctp][2]-mn)*rn*g[2]+bb[2],
                                                       (xf[ctp][3]-mn)*rn*g[3]+bb[3]);
                    }
                }
            }
        } else if (!LAST && wv == Mt) {
            // zero next layer's pad rows [Nn, 16*Mtn) in ybuf
            constexpr int Pn = P - 2, Nn = Pn * Pn, Mtn = (Nn + 15) / 16;
            constexpr int PadU = (16 * Mtn - Nn) * 36;
            unsigned* zb = (unsigned*)(ybuf + Nn * 72);
            for (int z = l; z < PadU; z += 64) zb[z] = 0;
        }
    }
    __syncthreads();

    if (LAST) {
        for (int idx = t; idx < 576; idx += NT) {
            const int d = idx / 9, rc = idx % 9;
            const int row = (rc / 3 + 3) * 9 + rc % 3 + 3;
            out[(size_t)b * 576 + idx] = xs[row * 68 + d];
        }
    }
}

__global__ __launch_bounds__(NT, 6) void vit_kernel(
    const float* __restrict__ x_in, const short* __restrict__ ws,
    const float* __restrict__ b_qkv, const float* __restrict__ b_o,
    const float* __restrict__ ln1_g, const float* __restrict__ ln1_b,
    const float* __restrict__ ln2_g, const float* __restrict__ ln2_b,
    const float* __restrict__ b1,    const float* __restrict__ b2,
    float* __restrict__ out)
{
    __shared__ __align__(16) float xs[81 * 68];     // 22032 B
    __shared__ __align__(16) short ybuf[96 * 72];   // 13824 B  (LN1 in)
    __shared__ __align__(16) short qbf[96 * 72];    // 13824 B  (attn-out)
    __shared__ __align__(16) short hb[96 * 8];      //  1536 B  (MLP hidden)

    const int b = blockIdx.x;
    const int t = threadIdx.x;

    // zero qbf once: layer-0 pad rows are read in phase D (finite-garbage ok,
    // but keep deterministic zeros)
    for (int idx = t; idx < 96 * 72; idx += NT) qbf[idx] = 0;

    const float* xin = x_in + (size_t)b * 5184;
    for (int q4 = t; q4 < 1296; q4 += NT) {
        const int i = q4 >> 4, dq = q4 & 15;
        *(f32x4*)&xs[i * 68 + dq * 4] = *(const f32x4*)&xin[i * 64 + dq * 4];
    }
    __syncthreads();

    layer_fn<81, 9, 0, true,  false>(xs, ybuf, qbf, hb, ws, b_qkv, b_o,
                                     ln1_g, ln1_b, ln2_g, ln2_b, b1, b2, out, b, t);
    layer_fn<49, 7, 1, false, false>(xs, ybuf, qbf, hb, ws, b_qkv, b_o,
                                     ln1_g, ln1_b, ln2_g, ln2_b, b1, b2, out, b, t);
    layer_fn<25, 5, 2, false, false>(xs, ybuf, qbf, hb, ws, b_qkv, b_o,
                                     ln1_g, ln1_b, ln2_g, ln2_b, b1, b2, out, b, t);
    layer_fn<9,  3, 3, false, true >(xs, ybuf, qbf, hb, ws, b_qkv, b_o,
                                     ln1_g, ln1_b, ln2_g, ln2_b, b1, b2, out, b, t);
}

extern "C" void kernel_launch(void* const* d_in, const int* in_sizes, int n_in,
                              void* d_out, int out_size, void* d_ws, size_t ws_size,
                              hipStream_t stream) {
    (void)n_in; (void)out_size; (void)ws_size;
    const float* x     = (const float*)d_in[0];
    const float* w_qkv = (const float*)d_in[1];
    const float* b_qkv = (const float*)d_in[2];
    const float* w_o   = (const float*)d_in[3];
    const float* b_o   = (const float*)d_in[4];
    const float* ln1_g = (const float*)d_in[5];
    const float* ln1_b = (const float*)d_in[6];
    const float* ln2_g = (const float*)d_in[7];
    const float* ln2_b = (const float*)d_in[8];
    const float* w1    = (const float*)d_in[9];
    const float* b1    = (const float*)d_in[10];
    const float* w2    = (const float*)d_in[11];
    const float* b2    = (const float*)d_in[12];
    short* ws = (short*)d_ws;

    prep_kernel<<<dim3((WS_TOT + 255) / 256), dim3(256), 0, stream>>>(w_qkv, w_o, w1, w2, ws);

    int B = in_sizes[0] / (81 * 64);
    vit_kernel<<<dim3(B), dim3(NT), 0, stream>>>(
        x, ws, b_qkv, b_o, ln1_g, ln1_b, ln2_g, ln2_b, b1, b2, (float*)d_out);
}

// Round 18
// 337.621 us; speedup vs baseline: 1.0162x; 1.0162x over previous
//
#include <hip/hip_runtime.h>
#include <hip/hip_bf16.h>
#include <math.h>

#define NT 512

typedef __attribute__((ext_vector_type(8))) short short8v;
typedef __attribute__((ext_vector_type(4))) short short4v;
typedef __attribute__((ext_vector_type(4))) float f32x4;
typedef __attribute__((ext_vector_type(2))) unsigned uint2v;
typedef __attribute__((ext_vector_type(4))) unsigned uint4v;

__device__ __forceinline__ unsigned short f2bf(float x) {   // prep kernel only
    unsigned u = __float_as_uint(x);
    unsigned r = ((u >> 16) & 1u) + 0x7FFFu;
    return (unsigned short)((u + r) >> 16);
}
__device__ __forceinline__ unsigned pk2(float a, float b) {
    __hip_bfloat162 h = __float22bfloat162_rn(make_float2(a, b));
    unsigned r;
    __builtin_memcpy(&r, &h, sizeof(r));
    return r;
}
__device__ __forceinline__ short bf1(float a) {
    __hip_bfloat16 h = __float2bfloat16(a);
    short r;
    __builtin_memcpy(&r, &h, sizeof(r));
    return r;
}
__device__ __forceinline__ float exp2fast(float x) {
#if __has_builtin(__builtin_amdgcn_exp2f)
    return __builtin_amdgcn_exp2f(x);
#else
    return exp2f(x);
#endif
}
__device__ __forceinline__ float rcpfast(float x) {
#if __has_builtin(__builtin_amdgcn_rcpf)
    return __builtin_amdgcn_rcpf(x);
#else
    return 1.0f / x;
#endif
}
// tanh-form gelu via exp2 + rcp (|err| vs erf-gelu ~3e-3, inside tolerance)
__device__ __forceinline__ float gelu_f(float x) {
    float x3 = x * x * x;
    float e = exp2fast(-2.3022079f * x - 0.1029432f * x3);
    return x * rcpfast(1.0f + e);
}
__device__ __forceinline__ f32x4 mfma32(short8v a, short8v b, f32x4 c) {
    return __builtin_amdgcn_mfma_f32_16x16x32_bf16(a, b, c, 0, 0, 0);
}
__device__ __forceinline__ f32x4 mfma16(short4v a, short4v b, f32x4 c) {
    return __builtin_amdgcn_mfma_f32_16x16x16bf16_1k(a, b, c, 0, 0, 0);
}

template<int M>
__device__ __forceinline__ void stats_tree(const f32x4* v, float& s1o, float& s2o) {
    float a[M], b[M];
    #pragma unroll
    for (int i = 0; i < M; ++i) {
        a[i] = (v[i][0] + v[i][1]) + (v[i][2] + v[i][3]);
        float q0 = v[i][0] * v[i][0], q1 = v[i][1] * v[i][1];
        float q2 = v[i][2] * v[i][2], q3 = v[i][3] * v[i][3];
        b[i] = (q0 + q1) + (q2 + q3);
    }
    #pragma unroll
    for (int s = 1; s < M; s *= 2)
        #pragma unroll
        for (int i = 0; i + s < M; i += 2 * s) { a[i] += a[i + s]; b[i] += b[i + s]; }
    s1o = a[0]; s2o = b[0];
}

// ws layout (bf16 shorts): wqkvT[L][192][64] @0 ; woT[L][64][64] @49152 ;
//                          w1T[L][16][64] @65536 (rows j>=8 zero) ; w2T[L][64][8] @69632
#define WS_WO 49152
#define WS_W1 65536
#define WS_W2 69632
#define WS_TOT 71680

__global__ __launch_bounds__(256) void prep_kernel(
    const float* __restrict__ w_qkv, const float* __restrict__ w_o,
    const float* __restrict__ w1, const float* __restrict__ w2,
    short* __restrict__ ws)
{
    int idx = blockIdx.x * 256 + threadIdx.x;
    if (idx < WS_WO) {
        int l = idx / 12288, r = idx % 12288, c = r >> 6, d = r & 63;
        ws[idx] = (short)f2bf(w_qkv[l * 12288 + d * 192 + c]);
    } else if (idx < WS_W1) {
        int k = idx - WS_WO; int l = k / 4096, r = k % 4096, c = r >> 6, d = r & 63;
        ws[idx] = (short)f2bf(w_o[l * 4096 + d * 64 + c]);
    } else if (idx < WS_W2) {
        int k = idx - WS_W1; int l = k / 1024, r = k % 1024, j = r >> 6, d = r & 63;
        ws[idx] = (j < 8) ? (short)f2bf(w1[l * 512 + d * 8 + j]) : (short)0;
    } else if (idx < WS_TOT) {
        int k = idx - WS_W2; int l = k / 512, r = k % 512, c = r >> 3, j = r & 7;
        ws[idx] = (short)f2bf(w2[l * 512 + j * 64 + c]);
    }
}

// LDS (51.2 KB -> 3 blocks/CU): xs fp32 [81][68] (full 9x9 grid, ring-indexed);
// ybuf bf16 [96][72] = LN1 input; qbf bf16 [96][72] = q (phase B) then attn-out
// (phase C overwrites per-head columns after use); hb bf16 [96][8] MLP hidden.
// k and v live in registers (per-wave GEMM, 2x duplicated across head pairs).
template<int N, int P, int L, bool FIRST, bool LAST>
__device__ __forceinline__ void layer_fn(
    float* __restrict__ xs, short* __restrict__ ybuf, short* __restrict__ qbf,
    short* __restrict__ hb, const short* __restrict__ ws,
    const float* __restrict__ b_qkv, const float* __restrict__ b_o,
    const float* __restrict__ ln1_g, const float* __restrict__ ln1_b,
    const float* __restrict__ ln2_g, const float* __restrict__ ln2_b,
    const float* __restrict__ b1,    const float* __restrict__ b2,
    float* __restrict__ out, int b, int t)
{
    constexpr int Mt = (N + 15) / 16;
    constexpr float SCL2E = 0.51010905835f;   // (HEAD_DIM/HEADS)^-0.5 * log2(e)
    const int wv = t >> 6, l = t & 63, lr = l & 15, lq = l >> 4;
    short8v zero8 = {};
    short4v zero4s = {};
    f32x4 zero4 = {0.f, 0.f, 0.f, 0.f};

    // ---- phase A (first layer only): LN1 -> ybuf. 4 lanes per token ----
    if (FIRST) {
        if (t < 64 * Mt) {
            const int token = t >> 2, part = t & 3, d0 = part * 16;
            short* yrow = ybuf + token * 72 + d0;
            if (token < N) {
                const int row = (token / P + L) * 9 + token % P + L;
                const float* xr = xs + row * 68 + d0;
                f32x4 v[4];
                #pragma unroll
                for (int k = 0; k < 4; ++k) v[k] = *(const f32x4*)(xr + 4 * k);
                float s1, s2;
                stats_tree<4>(v, s1, s2);
                s1 += __shfl_xor(s1, 1); s2 += __shfl_xor(s2, 1);
                s1 += __shfl_xor(s1, 2); s2 += __shfl_xor(s2, 2);
                const float m = s1 * 0.015625f;
                const float r = rsqrtf(s2 * 0.015625f - m * m + 1e-5f);
                uint4v w0, w1v;
                #pragma unroll
                for (int k = 0; k < 4; ++k) {
                    f32x4 g  = *(const f32x4*)&ln1_g[L * 64 + d0 + 4 * k];
                    f32x4 bb = *(const f32x4*)&ln1_b[L * 64 + d0 + 4 * k];
                    unsigned p0 = pk2((v[k][0]-m)*r*g[0]+bb[0], (v[k][1]-m)*r*g[1]+bb[1]);
                    unsigned p1 = pk2((v[k][2]-m)*r*g[2]+bb[2], (v[k][3]-m)*r*g[3]+bb[3]);
                    if (k == 0) { w0.x = p0; w0.y = p1; }
                    else if (k == 1) { w0.z = p0; w0.w = p1; }
                    else if (k == 2) { w1v.x = p0; w1v.y = p1; }
                    else { w1v.z = p0; w1v.w = p1; }
                }
                *(uint4v*)yrow = w0;
                *(uint4v*)(yrow + 8) = w1v;
            } else {
                uint4v z = {};
                *(uint4v*)yrow = z;
                *(uint4v*)(yrow + 8) = z;
            }
        }
        __syncthreads();
    }

    // ---- phase B: q GEMM only (swapped: lane=token, packed channel writes).
    //      Scale*log2e folded. k/v are computed in-register in phase C. ----
    {
        const short* wqL = ws + L * 12288;
        for (int u = wv; u < Mt * 4; u += 8) {
            const int mt = u >> 2, ct = u & 3;
            const short* yr = &ybuf[(16 * mt + lr) * 72 + lq * 8];
            short8v y0 = *(const short8v*)yr, y1 = *(const short8v*)(yr + 32);
            const short* wr = &wqL[(16 * ct + lr) * 64 + lq * 8];
            short8v w0 = *(const short8v*)wr, w1 = *(const short8v*)(wr + 32);
            f32x4 acc = mfma32(w0, y0, zero4);
            acc = mfma32(w1, y1, acc);
            f32x4 bq = *(const f32x4*)&b_qkv[L * 192 + 16 * ct + lq * 4];
            const int i = 16 * mt + lr;   // token
            unsigned p0 = pk2((acc[0]+bq[0])*SCL2E, (acc[1]+bq[1])*SCL2E);
            unsigned p1 = pk2((acc[2]+bq[2])*SCL2E, (acc[3]+bq[3])*SCL2E);
            unsigned* dst = (unsigned*)&qbf[i * 72 + 16 * ct + lq * 4];
            dst[0] = p0; dst[1] = p1;
        }
    }
    __syncthreads();

    // ---- phase C: fused k/v-GEMM + attention. wave = head h.
    //      k,v in registers; q read from qbf directly in _1k B-fragment layout;
    //      PV fused into the scores loop (no pkk array -> minimal live set);
    //      attn-out overwrites qbf's own-head columns. ----
    {
        const int h = wv, a = h & 1, ct = h >> 1;
        const short* wqL = ws + L * 12288;

        // V pass: unswapped GEMM -> D fragment == PV A-operand fragment directly
        short4v vf[Mt];
        {
            const short* wvr = &wqL[(128 + 16 * ct + lr) * 64 + lq * 8];
            short8v wv0 = *(const short8v*)wvr, wv1 = *(const short8v*)(wvr + 32);
            const float vbi = b_qkv[L * 192 + 128 + 16 * ct + lr];
            #pragma unroll
            for (int mt = 0; mt < Mt; ++mt) {
                const short* yr = &ybuf[(16 * mt + lr) * 72 + lq * 8];
                short8v y0 = *(const short8v*)yr, y1 = *(const short8v*)(yr + 32);
                f32x4 acc = mfma32(y0, wv0, zero4);
                acc = mfma32(y1, wv1, acc);
                uint2v u;
                u.x = pk2(acc[0] + vbi, acc[1] + vbi);
                u.y = pk2(acc[2] + vbi, acc[3] + vbi);
                vf[mt] = __builtin_bit_cast(short4v, u);
            }
        }
        // K pass: swapped GEMM, redistribute (2 shfl) -> scores A fragment
        const int srcl = lr + 32 * a + (l & 16);
        uint2v kf[Mt];
        {
            const short* wkr = &wqL[(64 + 16 * ct + lr) * 64 + lq * 8];
            short8v wk0 = *(const short8v*)wkr, wk1 = *(const short8v*)(wkr + 32);
            f32x4 kb = *(const f32x4*)&b_qkv[L * 192 + 64 + 16 * ct + lq * 4];
            #pragma unroll
            for (int mt = 0; mt < Mt; ++mt) {
                const short* yr = &ybuf[(16 * mt + lr) * 72 + lq * 8];
                short8v y0 = *(const short8v*)yr, y1 = *(const short8v*)(yr + 32);
                f32x4 acc = mfma32(wk0, y0, zero4);
                acc = mfma32(wk1, y1, acc);
                unsigned ka = pk2(acc[0] + kb[0], acc[1] + kb[1]);
                unsigned kc = pk2(acc[2] + kb[2], acc[3] + kb[3]);
                unsigned u0 = (unsigned)__shfl((int)ka, srcl);
                unsigned u1 = (unsigned)__shfl((int)kc, srcl);
                uint2v kv; kv.x = (l < 32) ? u0 : 0u; kv.y = (l < 32) ? u1 : 0u;
                kf[mt] = kv;
            }
        }
        // scores + softmax + PV per query tile (PV fused per-jt; no P array)
        for (int mt = 0; mt < Mt; ++mt) {
            short4v qv = zero4s;
            if (l < 32)
                qv = *(const short4v*)&qbf[(16 * mt + lr) * 72 + 8 * h + 4 * ((l >> 4) & 1)];
            float psA = 0.f, psB = 0.f;
            f32x4 po0 = zero4, po1 = zero4;
            #pragma unroll
            for (int jt = 0; jt < Mt; ++jt) {
                f32x4 s = mfma16(__builtin_bit_cast(short4v, kf[jt]), qv, zero4);
                float e0 = exp2fast(s[0]), e1 = exp2fast(s[1]);
                float e2 = exp2fast(s[2]), e3 = exp2fast(s[3]);
                if (jt == Mt - 1) {   // only the last tile contains pad keys
                    const int j0 = 16 * jt + lq * 4;
                    e0 = (j0 + 0 < N) ? e0 : 0.f;
                    e1 = (j0 + 1 < N) ? e1 : 0.f;
                    e2 = (j0 + 2 < N) ? e2 : 0.f;
                    e3 = (j0 + 3 < N) ? e3 : 0.f;
                }
                psA += e0 + e1; psB += e2 + e3;
                uint2v pv; pv.x = pk2(e0, e1); pv.y = pk2(e2, e3);
                short4v bv = __builtin_bit_cast(short4v, pv);
                if (jt & 1) po1 = mfma16(vf[jt], bv, po1);
                else        po0 = mfma16(vf[jt], bv, po0);
            }
            float psum = psA + psB;
            float den = psum + __shfl_xor(psum, 16);
            den += __shfl_xor(den, 32);
            const float dinv = rcpfast(den);
            if ((lq >> 1) == a) {
                const int i = 16 * mt + lr;
                if (i < N) {
                    unsigned q0 = pk2((po0[0] + po1[0]) * dinv, (po0[1] + po1[1]) * dinv);
                    unsigned q1 = pk2((po0[2] + po1[2]) * dinv, (po0[3] + po1[3]) * dinv);
                    unsigned* dst = (unsigned*)&qbf[i * 72 + 8 * h + (lq & 1) * 4];
                    dst[0] = q0; dst[1] = q1;
                }
            }
        }
    }
    __syncthreads();

    // ---- phase D (fused, wave-local): w_o + residual + LN2 + MLP + residual
    //      + LN1-of-next-layer written into ybuf (dead after phase B). ----
    {
        if (wv < Mt) {
            const int mt = wv;
            const int i = 16 * mt + lr;          // token (this layer)
            const bool iok = (i < N);
            const int xrow = iok ? (i / P + L) * 9 + (i % P) + L : 0;
            float* xp = xs + xrow * 68;
            const short* yr = &qbf[i * 72 + lq * 8];   // attn-out
            short8v y0 = *(const short8v*)yr;
            short8v y1 = *(const short8v*)(yr + 32);
            const short* woL = ws + WS_WO + L * 4096;
            f32x4 xv[4];
            #pragma unroll
            for (int ctp = 0; ctp < 4; ++ctp) {
                const short* wr = &woL[(16 * ctp + lr) * 64 + lq * 8];
                f32x4 acc = mfma32(*(const short8v*)wr, y0, zero4);
                acc = mfma32(*(const short8v*)(wr + 32), y1, acc);
                f32x4 bo = *(const f32x4*)&b_o[L * 64 + 16 * ctp + 4 * lq];
                f32x4 xc = zero4;
                if (iok) xc = *(const f32x4*)(xp + 16 * ctp + 4 * lq);
                #pragma unroll
                for (int rg = 0; rg < 4; ++rg) xc[rg] += acc[rg] + bo[rg];
                xv[ctp] = xc;
            }
            float s1, s2;
            stats_tree<4>(xv, s1, s2);
            s1 += __shfl_xor(s1, 16); s2 += __shfl_xor(s2, 16);
            s1 += __shfl_xor(s1, 32); s2 += __shfl_xor(s2, 32);
            const float m = s1 * 0.015625f;
            const float r = rsqrtf(s2 * 0.015625f - m * m + 1e-5f);
            unsigned* abw = (unsigned*)&qbf[i * 72];
            #pragma unroll
            for (int ctp = 0; ctp < 4; ++ctp) {
                f32x4 g  = *(const f32x4*)&ln2_g[L * 64 + 16 * ctp + 4 * lq];
                f32x4 bb = *(const f32x4*)&ln2_b[L * 64 + 16 * ctp + 4 * lq];
                abw[8 * ctp + 2 * lq]     = pk2((xv[ctp][0]-m)*r*g[0]+bb[0],
                                                (xv[ctp][1]-m)*r*g[1]+bb[1]);
                abw[8 * ctp + 2 * lq + 1] = pk2((xv[ctp][2]-m)*r*g[2]+bb[2],
                                                (xv[ctp][3]-m)*r*g[3]+bb[3]);
            }
            // MLP up (same-wave LDS round-trip, matched unsigned types)
            uint4v ua0 = *(const uint4v*)(abw + 4 * lq);
            uint4v ua1 = *(const uint4v*)(abw + 16 + 4 * lq);
            const short* w1L = ws + WS_W1 + L * 1024;
            short8v a10 = __builtin_bit_cast(short8v, ua0);
            short8v a11 = __builtin_bit_cast(short8v, ua1);
            short8v b10 = *(const short8v*)&w1L[lr * 64 + lq * 8];
            short8v b11 = *(const short8v*)&w1L[lr * 64 + lq * 8 + 32];
            f32x4 hA = mfma32(a10, b10, zero4);
            hA = mfma32(a11, b11, hA);
            if (lr < 8) {
                const float bg = b1[L * 8 + lr];
                #pragma unroll
                for (int rg = 0; rg < 4; ++rg)
                    hb[(16 * mt + 4 * lq + rg) * 8 + lr] = bf1(gelu_f(hA[rg] + bg));
            }
            // MLP down, swapped orientation: D[ch 16ctp+4lq+rg][tok lr]
            short8v hbf = (lq == 0) ? *(const short8v*)&hb[(16 * mt + lr) * 8] : zero8;
            const short* w2L = ws + WS_W2 + L * 512;
            f32x4 xf[4];
            #pragma unroll
            for (int ctp = 0; ctp < 4; ++ctp) {
                short8v a2 = (lq == 0) ? *(const short8v*)&w2L[(16 * ctp + lr) * 8] : zero8;
                f32x4 dacc = mfma32(a2, hbf, zero4);
                f32x4 b2v = *(const f32x4*)&b2[L * 64 + 16 * ctp + 4 * lq];
                #pragma unroll
                for (int rg = 0; rg < 4; ++rg) xf[ctp][rg] = xv[ctp][rg] + dacc[rg] + b2v[rg];
                if (iok) *(f32x4*)(xp + 16 * ctp + 4 * lq) = xf[ctp];
            }
            if (!LAST) {
                // LN1 of the next layer, straight from registers -> ybuf
                float t1, t2;
                stats_tree<4>(xf, t1, t2);
                t1 += __shfl_xor(t1, 16); t2 += __shfl_xor(t2, 16);
                t1 += __shfl_xor(t1, 32); t2 += __shfl_xor(t2, 32);
                const float mn = t1 * 0.015625f;
                const float rn = rsqrtf(t2 * 0.015625f - mn * mn + 1e-5f);
                const int r_ = i / P, c_ = i % P;
                const bool vok = iok && r_ >= 1 && r_ <= P - 2 && c_ >= 1 && c_ <= P - 2;
                if (vok) {
                    const int j = (r_ - 1) * (P - 2) + (c_ - 1);
                    unsigned* yw = (unsigned*)&ybuf[j * 72];
                    #pragma unroll
                    for (int ctp = 0; ctp < 4; ++ctp) {
                        f32x4 g  = *(const f32x4*)&ln1_g[(L + 1) * 64 + 16 * ctp + 4 * lq];
                        f32x4 bb = *(const f32x4*)&ln1_b[(L + 1) * 64 + 16 * ctp + 4 * lq];
                        yw[8 * ctp + 2 * lq]     = pk2((xf[ctp][0]-mn)*rn*g[0]+bb[0],
                                                       (xf[ctp][1]-mn)*rn*g[1]+bb[1]);
                        yw[8 * ctp + 2 * lq + 1] = pk2((xf[ctp][2]-mn)*rn*g[2]+bb[2],
                                                       (xf[ctp][3]-mn)*rn*g[3]+bb[3]);
                    }
                }
            }
        } else if (!LAST && wv == Mt) {
            // zero next layer's pad rows [Nn, 16*Mtn) in ybuf
            constexpr int Pn = P - 2, Nn = Pn * Pn, Mtn = (Nn + 15) / 16;
            constexpr int PadU = (16 * Mtn - Nn) * 36;
            unsigned* zb = (unsigned*)(ybuf + Nn * 72);
            for (int z = l; z < PadU; z += 64) zb[z] = 0;
        }
    }
    __syncthreads();

    if (LAST) {
        for (int idx = t; idx < 576; idx += NT) {
            const int d = idx / 9, rc = idx % 9;
            const int row = (rc / 3 + 3) * 9 + rc % 3 + 3;
            out[(size_t)b * 576 + idx] = xs[row * 68 + d];
        }
    }
}

__global__ __launch_bounds__(NT, 4) void vit_kernel(
    const float* __restrict__ x_in, const short* __restrict__ ws,
    const float* __restrict__ b_qkv, const float* __restrict__ b_o,
    const float* __restrict__ ln1_g, const float* __restrict__ ln1_b,
    const float* __restrict__ ln2_g, const float* __restrict__ ln2_b,
    const float* __restrict__ b1,    const float* __restrict__ b2,
    float* __restrict__ out)
{
    __shared__ __align__(16) float xs[81 * 68];     // 22032 B
    __shared__ __align__(16) short ybuf[96 * 72];   // 13824 B  (LN1 in)
    __shared__ __align__(16) short qbf[96 * 72];    // 13824 B  (q, then attn-out)
    __shared__ __align__(16) short hb[96 * 8];      //  1536 B  (MLP hidden)

    const int b = blockIdx.x;
    const int t = threadIdx.x;

    const float* xin = x_in + (size_t)b * 5184;
    for (int q4 = t; q4 < 1296; q4 += NT) {
        const int i = q4 >> 4, dq = q4 & 15;
        *(f32x4*)&xs[i * 68 + dq * 4] = *(const f32x4*)&xin[i * 64 + dq * 4];
    }
    __syncthreads();

    layer_fn<81, 9, 0, true,  false>(xs, ybuf, qbf, hb, ws, b_qkv, b_o,
                                     ln1_g, ln1_b, ln2_g, ln2_b, b1, b2, out, b, t);
    layer_fn<49, 7, 1, false, false>(xs, ybuf, qbf, hb, ws, b_qkv, b_o,
                                     ln1_g, ln1_b, ln2_g, ln2_b, b1, b2, out, b, t);
    layer_fn<25, 5, 2, false, false>(xs, ybuf, qbf, hb, ws, b_qkv, b_o,
                                     ln1_g, ln1_b, ln2_g, ln2_b, b1, b2, out, b, t);
    layer_fn<9,  3, 3, false, true >(xs, ybuf, qbf, hb, ws, b_qkv, b_o,
                                     ln1_g, ln1_b, ln2_g, ln2_b, b1, b2, out, b, t);
}

extern "C" void kernel_launch(void* const* d_in, const int* in_sizes, int n_in,
                              void* d_out, int out_size, void* d_ws, size_t ws_size,
                              hipStream_t stream) {
    (void)n_in; (void)out_size; (void)ws_size;
    const float* x     = (const float*)d_in[0];
    const float* w_qkv = (const float*)d_in[1];
    const float* b_qkv = (const float*)d_in[2];
    const float* w_o   = (const float*)d_in[3];
    const float* b_o   = (const float*)d_in[4];
    const float* ln1_g = (const float*)d_in[5];
    const float* ln1_b = (const float*)d_in[6];
    const float* ln2_g = (const float*)d_in[7];
    const float* ln2_b = (const float*)d_in[8];
    const float* w1    = (const float*)d_in[9];
    const float* b1    = (const float*)d_in[10];
    const float* w2    = (const float*)d_in[11];
    const float* b2    = (const float*)d_in[12];
    short* ws = (short*)d_ws;

    prep_kernel<<<dim3((WS_TOT + 255) / 256), dim3(256), 0, stream>>>(w_qkv, w_o, w1, w2, ws);

    int B = in_sizes[0] / (81 * 64);
    vit_kernel<<<dim3(B), dim3(NT), 0, stream>>>(
        x, ws, b_qkv, b_o, ln1_g, ln1_b, ln2_g, ln2_b, b1, b2, (float*)d_out);
}

// Round 19
// 336.569 us; speedup vs baseline: 1.0194x; 1.0031x over previous
//
#include <hip/hip_runtime.h>
#include <hip/hip_bf16.h>
#include <math.h>

#define NT 512

typedef __attribute__((ext_vector_type(8))) short short8v;
typedef __attribute__((ext_vector_type(4))) short short4v;
typedef __attribute__((ext_vector_type(4))) float f32x4;
typedef __attribute__((ext_vector_type(2))) unsigned uint2v;
typedef __attribute__((ext_vector_type(4))) unsigned uint4v;

__device__ __forceinline__ unsigned short f2bf(float x) {   // prep kernel only
    unsigned u = __float_as_uint(x);
    unsigned r = ((u >> 16) & 1u) + 0x7FFFu;
    return (unsigned short)((u + r) >> 16);
}
__device__ __forceinline__ unsigned pk2(float a, float b) {
    __hip_bfloat162 h = __float22bfloat162_rn(make_float2(a, b));
    unsigned r;
    __builtin_memcpy(&r, &h, sizeof(r));
    return r;
}
__device__ __forceinline__ short bf1(float a) {
    __hip_bfloat16 h = __float2bfloat16(a);
    short r;
    __builtin_memcpy(&r, &h, sizeof(r));
    return r;
}
__device__ __forceinline__ float exp2fast(float x) {
#if __has_builtin(__builtin_amdgcn_exp2f)
    return __builtin_amdgcn_exp2f(x);
#else
    return exp2f(x);
#endif
}
__device__ __forceinline__ float rcpfast(float x) {
#if __has_builtin(__builtin_amdgcn_rcpf)
    return __builtin_amdgcn_rcpf(x);
#else
    return 1.0f / x;
#endif
}
// tanh-form gelu via exp2 + rcp (|err| vs erf-gelu ~3e-3, inside tolerance)
__device__ __forceinline__ float gelu_f(float x) {
    float x3 = x * x * x;
    float e = exp2fast(-2.3022079f * x - 0.1029432f * x3);
    return x * rcpfast(1.0f + e);
}
__device__ __forceinline__ f32x4 mfma32(short8v a, short8v b, f32x4 c) {
    return __builtin_amdgcn_mfma_f32_16x16x32_bf16(a, b, c, 0, 0, 0);
}
__device__ __forceinline__ f32x4 mfma16(short4v a, short4v b, f32x4 c) {
    return __builtin_amdgcn_mfma_f32_16x16x16bf16_1k(a, b, c, 0, 0, 0);
}

template<int M>
__device__ __forceinline__ void stats_tree(const f32x4* v, float& s1o, float& s2o) {
    float a[M], b[M];
    #pragma unroll
    for (int i = 0; i < M; ++i) {
        a[i] = (v[i][0] + v[i][1]) + (v[i][2] + v[i][3]);
        float q0 = v[i][0] * v[i][0], q1 = v[i][1] * v[i][1];
        float q2 = v[i][2] * v[i][2], q3 = v[i][3] * v[i][3];
        b[i] = (q0 + q1) + (q2 + q3);
    }
    #pragma unroll
    for (int s = 1; s < M; s *= 2)
        #pragma unroll
        for (int i = 0; i + s < M; i += 2 * s) { a[i] += a[i + s]; b[i] += b[i + s]; }
    s1o = a[0]; s2o = b[0];
}

// ws layout (bf16 shorts): wqkvT[L][192][64] @0 ; woT[L][64][64] @49152 ;
//                          w1T[L][16][64] @65536 (rows j>=8 zero) ; w2T[L][64][8] @69632
#define WS_WO 49152
#define WS_W1 65536
#define WS_W2 69632
#define WS_TOT 71680

__global__ __launch_bounds__(256) void prep_kernel(
    const float* __restrict__ w_qkv, const float* __restrict__ w_o,
    const float* __restrict__ w1, const float* __restrict__ w2,
    short* __restrict__ ws)
{
    int idx = blockIdx.x * 256 + threadIdx.x;
    if (idx < WS_WO) {
        int l = idx / 12288, r = idx % 12288, c = r >> 6, d = r & 63;
        ws[idx] = (short)f2bf(w_qkv[l * 12288 + d * 192 + c]);
    } else if (idx < WS_W1) {
        int k = idx - WS_WO; int l = k / 4096, r = k % 4096, c = r >> 6, d = r & 63;
        ws[idx] = (short)f2bf(w_o[l * 4096 + d * 64 + c]);
    } else if (idx < WS_W2) {
        int k = idx - WS_W1; int l = k / 1024, r = k % 1024, j = r >> 6, d = r & 63;
        ws[idx] = (j < 8) ? (short)f2bf(w1[l * 512 + d * 8 + j]) : (short)0;
    } else if (idx < WS_TOT) {
        int k = idx - WS_W2; int l = k / 512, r = k % 512, c = r >> 3, j = r & 7;
        ws[idx] = (short)f2bf(w2[l * 512 + j * 64 + c]);
    }
}

// LDS (51.2 KB -> 3 blocks/CU): xs fp32 [81][68] (full 9x9 grid, ring-indexed);
// ybuf bf16 [96][72] = LN1 input; qbf bf16 [96][72] = q (phase B) then attn-out
// (phase C overwrites per-head columns after use); hb bf16 [96][8] MLP hidden.
// k and v live in registers (per-wave GEMM, 2x duplicated across head pairs).
template<int N, int P, int L, bool FIRST, bool LAST>
__device__ __forceinline__ void layer_fn(
    float* __restrict__ xs, short* __restrict__ ybuf, short* __restrict__ qbf,
    short* __restrict__ hb, const short* __restrict__ ws,
    const float* __restrict__ b_qkv, const float* __restrict__ b_o,
    const float* __restrict__ ln1_g, const float* __restrict__ ln1_b,
    const float* __restrict__ ln2_g, const float* __restrict__ ln2_b,
    const float* __restrict__ b1,    const float* __restrict__ b2,
    float* __restrict__ out, int b, int t)
{
    constexpr int Mt = (N + 15) / 16;
    constexpr float SCL2E = 0.51010905835f;   // (HEAD_DIM/HEADS)^-0.5 * log2(e)
    const int wv = t >> 6, l = t & 63, lr = l & 15, lq = l >> 4;
    short8v zero8 = {};
    short4v zero4s = {};
    f32x4 zero4 = {0.f, 0.f, 0.f, 0.f};

    // ---- phase A (first layer only): LN1 -> ybuf. 4 lanes per token ----
    if (FIRST) {
        if (t < 64 * Mt) {
            const int token = t >> 2, part = t & 3, d0 = part * 16;
            short* yrow = ybuf + token * 72 + d0;
            if (token < N) {
                const int row = (token / P + L) * 9 + token % P + L;
                const float* xr = xs + row * 68 + d0;
                f32x4 v[4];
                #pragma unroll
                for (int k = 0; k < 4; ++k) v[k] = *(const f32x4*)(xr + 4 * k);
                float s1, s2;
                stats_tree<4>(v, s1, s2);
                s1 += __shfl_xor(s1, 1); s2 += __shfl_xor(s2, 1);
                s1 += __shfl_xor(s1, 2); s2 += __shfl_xor(s2, 2);
                const float m = s1 * 0.015625f;
                const float r = rsqrtf(s2 * 0.015625f - m * m + 1e-5f);
                uint4v w0, w1v;
                #pragma unroll
                for (int k = 0; k < 4; ++k) {
                    f32x4 g  = *(const f32x4*)&ln1_g[L * 64 + d0 + 4 * k];
                    f32x4 bb = *(const f32x4*)&ln1_b[L * 64 + d0 + 4 * k];
                    unsigned p0 = pk2((v[k][0]-m)*r*g[0]+bb[0], (v[k][1]-m)*r*g[1]+bb[1]);
                    unsigned p1 = pk2((v[k][2]-m)*r*g[2]+bb[2], (v[k][3]-m)*r*g[3]+bb[3]);
                    if (k == 0) { w0.x = p0; w0.y = p1; }
                    else if (k == 1) { w0.z = p0; w0.w = p1; }
                    else if (k == 2) { w1v.x = p0; w1v.y = p1; }
                    else { w1v.z = p0; w1v.w = p1; }
                }
                *(uint4v*)yrow = w0;
                *(uint4v*)(yrow + 8) = w1v;
            } else {
                uint4v z = {};
                *(uint4v*)yrow = z;
                *(uint4v*)(yrow + 8) = z;
            }
        }
        __syncthreads();
    }

    // ---- phase B: q GEMM only (swapped: lane=token, packed channel writes).
    //      Scale*log2e folded. k/v are computed in-register in phase C. ----
    {
        const short* wqL = ws + L * 12288;
        for (int u = wv; u < Mt * 4; u += 8) {
            const int mt = u >> 2, ct = u & 3;
            const short* yr = &ybuf[(16 * mt + lr) * 72 + lq * 8];
            short8v y0 = *(const short8v*)yr, y1 = *(const short8v*)(yr + 32);
            const short* wr = &wqL[(16 * ct + lr) * 64 + lq * 8];
            short8v w0 = *(const short8v*)wr, w1 = *(const short8v*)(wr + 32);
            f32x4 acc = mfma32(w0, y0, zero4);
            acc = mfma32(w1, y1, acc);
            f32x4 bq = *(const f32x4*)&b_qkv[L * 192 + 16 * ct + lq * 4];
            const int i = 16 * mt + lr;   // token
            unsigned p0 = pk2((acc[0]+bq[0])*SCL2E, (acc[1]+bq[1])*SCL2E);
            unsigned p1 = pk2((acc[2]+bq[2])*SCL2E, (acc[3]+bq[3])*SCL2E);
            unsigned* dst = (unsigned*)&qbf[i * 72 + 16 * ct + lq * 4];
            dst[0] = p0; dst[1] = p1;
        }
    }
    __syncthreads();

    // ---- phase C: fused k/v-GEMM + attention. wave = head h.
    //      k,v in registers; q read from qbf directly in _1k B-fragment layout;
    //      PV fused into the scores loop (no pkk array -> minimal live set);
    //      attn-out overwrites qbf's own-head columns. ----
    {
        const int h = wv, a = h & 1, ct = h >> 1;
        const short* wqL = ws + L * 12288;

        // V pass: unswapped GEMM -> D fragment == PV A-operand fragment directly
        short4v vf[Mt];
        {
            const short* wvr = &wqL[(128 + 16 * ct + lr) * 64 + lq * 8];
            short8v wv0 = *(const short8v*)wvr, wv1 = *(const short8v*)(wvr + 32);
            const float vbi = b_qkv[L * 192 + 128 + 16 * ct + lr];
            #pragma unroll
            for (int mt = 0; mt < Mt; ++mt) {
                const short* yr = &ybuf[(16 * mt + lr) * 72 + lq * 8];
                short8v y0 = *(const short8v*)yr, y1 = *(const short8v*)(yr + 32);
                f32x4 acc = mfma32(y0, wv0, zero4);
                acc = mfma32(y1, wv1, acc);
                uint2v u;
                u.x = pk2(acc[0] + vbi, acc[1] + vbi);
                u.y = pk2(acc[2] + vbi, acc[3] + vbi);
                vf[mt] = __builtin_bit_cast(short4v, u);
            }
        }
        // K pass: swapped GEMM, redistribute (2 shfl) -> scores A fragment
        const int srcl = lr + 32 * a + (l & 16);
        uint2v kf[Mt];
        {
            const short* wkr = &wqL[(64 + 16 * ct + lr) * 64 + lq * 8];
            short8v wk0 = *(const short8v*)wkr, wk1 = *(const short8v*)(wkr + 32);
            f32x4 kb = *(const f32x4*)&b_qkv[L * 192 + 64 + 16 * ct + lq * 4];
            #pragma unroll
            for (int mt = 0; mt < Mt; ++mt) {
                const short* yr = &ybuf[(16 * mt + lr) * 72 + lq * 8];
                short8v y0 = *(const short8v*)yr, y1 = *(const short8v*)(yr + 32);
                f32x4 acc = mfma32(wk0, y0, zero4);
                acc = mfma32(wk1, y1, acc);
                unsigned ka = pk2(acc[0] + kb[0], acc[1] + kb[1]);
                unsigned kc = pk2(acc[2] + kb[2], acc[3] + kb[3]);
                unsigned u0 = (unsigned)__shfl((int)ka, srcl);
                unsigned u1 = (unsigned)__shfl((int)kc, srcl);
                uint2v kv; kv.x = (l < 32) ? u0 : 0u; kv.y = (l < 32) ? u1 : 0u;
                kf[mt] = kv;
            }
        }
        // scores + softmax + PV per query tile (PV fused per-jt; no P array)
        for (int mt = 0; mt < Mt; ++mt) {
            short4v qv = zero4s;
            if (l < 32)
                qv = *(const short4v*)&qbf[(16 * mt + lr) * 72 + 8 * h + 4 * ((l >> 4) & 1)];
            float psA = 0.f, psB = 0.f;
            f32x4 po0 = zero4, po1 = zero4;
            #pragma unroll
            for (int jt = 0; jt < Mt; ++jt) {
                f32x4 s = mfma16(__builtin_bit_cast(short4v, kf[jt]), qv, zero4);
                float e0 = exp2fast(s[0]), e1 = exp2fast(s[1]);
                float e2 = exp2fast(s[2]), e3 = exp2fast(s[3]);
                if (jt == Mt - 1) {   // only the last tile contains pad keys
                    const int j0 = 16 * jt + lq * 4;
                    e0 = (j0 + 0 < N) ? e0 : 0.f;
                    e1 = (j0 + 1 < N) ? e1 : 0.f;
                    e2 = (j0 + 2 < N) ? e2 : 0.f;
                    e3 = (j0 + 3 < N) ? e3 : 0.f;
                }
                psA += e0 + e1; psB += e2 + e3;
                uint2v pv; pv.x = pk2(e0, e1); pv.y = pk2(e2, e3);
                short4v bv = __builtin_bit_cast(short4v, pv);
                if (jt & 1) po1 = mfma16(vf[jt], bv, po1);
                else        po0 = mfma16(vf[jt], bv, po0);
            }
            float psum = psA + psB;
            float den = psum + __shfl_xor(psum, 16);
            den += __shfl_xor(den, 32);
            const float dinv = rcpfast(den);
            if ((lq >> 1) == a) {
                const int i = 16 * mt + lr;
                if (i < N) {
                    unsigned q0 = pk2((po0[0] + po1[0]) * dinv, (po0[1] + po1[1]) * dinv);
                    unsigned q1 = pk2((po0[2] + po1[2]) * dinv, (po0[3] + po1[3]) * dinv);
                    unsigned* dst = (unsigned*)&qbf[i * 72 + 8 * h + (lq & 1) * 4];
                    dst[0] = q0; dst[1] = q1;
                }
            }
        }
    }
    __syncthreads();

    // ---- phase D (fused, wave-local): w_o + residual + LN2 + MLP + residual
    //      + LN1-of-next-layer written into ybuf (dead after phase B). ----
    {
        if (wv < Mt) {
            const int mt = wv;
            const int i = 16 * mt + lr;          // token (this layer)
            const bool iok = (i < N);
            const int xrow = iok ? (i / P + L) * 9 + (i % P) + L : 0;
            float* xp = xs + xrow * 68;
            const short* yr = &qbf[i * 72 + lq * 8];   // attn-out
            short8v y0 = *(const short8v*)yr;
            short8v y1 = *(const short8v*)(yr + 32);
            const short* woL = ws + WS_WO + L * 4096;
            f32x4 xv[4];
            #pragma unroll
            for (int ctp = 0; ctp < 4; ++ctp) {
                const short* wr = &woL[(16 * ctp + lr) * 64 + lq * 8];
                f32x4 acc = mfma32(*(const short8v*)wr, y0, zero4);
                acc = mfma32(*(const short8v*)(wr + 32), y1, acc);
                f32x4 bo = *(const f32x4*)&b_o[L * 64 + 16 * ctp + 4 * lq];
                f32x4 xc = zero4;
                if (iok) xc = *(const f32x4*)(xp + 16 * ctp + 4 * lq);
                #pragma unroll
                for (int rg = 0; rg < 4; ++rg) xc[rg] += acc[rg] + bo[rg];
                xv[ctp] = xc;
            }
            float s1, s2;
            stats_tree<4>(xv, s1, s2);
            s1 += __shfl_xor(s1, 16); s2 += __shfl_xor(s2, 16);
            s1 += __shfl_xor(s1, 32); s2 += __shfl_xor(s2, 32);
            const float m = s1 * 0.015625f;
            const float r = rsqrtf(s2 * 0.015625f - m * m + 1e-5f);
            unsigned* abw = (unsigned*)&qbf[i * 72];
            #pragma unroll
            for (int ctp = 0; ctp < 4; ++ctp) {
                f32x4 g  = *(const f32x4*)&ln2_g[L * 64 + 16 * ctp + 4 * lq];
                f32x4 bb = *(const f32x4*)&ln2_b[L * 64 + 16 * ctp + 4 * lq];
                abw[8 * ctp + 2 * lq]     = pk2((xv[ctp][0]-m)*r*g[0]+bb[0],
                                                (xv[ctp][1]-m)*r*g[1]+bb[1]);
                abw[8 * ctp + 2 * lq + 1] = pk2((xv[ctp][2]-m)*r*g[2]+bb[2],
                                                (xv[ctp][3]-m)*r*g[3]+bb[3]);
            }
            // MLP up (same-wave LDS round-trip, matched unsigned types)
            uint4v ua0 = *(const uint4v*)(abw + 4 * lq);
            uint4v ua1 = *(const uint4v*)(abw + 16 + 4 * lq);
            const short* w1L = ws + WS_W1 + L * 1024;
            short8v a10 = __builtin_bit_cast(short8v, ua0);
            short8v a11 = __builtin_bit_cast(short8v, ua1);
            short8v b10 = *(const short8v*)&w1L[lr * 64 + lq * 8];
            short8v b11 = *(const short8v*)&w1L[lr * 64 + lq * 8 + 32];
            f32x4 hA = mfma32(a10, b10, zero4);
            hA = mfma32(a11, b11, hA);
            if (lr < 8) {
                const float bg = b1[L * 8 + lr];
                #pragma unroll
                for (int rg = 0; rg < 4; ++rg)
                    hb[(16 * mt + 4 * lq + rg) * 8 + lr] = bf1(gelu_f(hA[rg] + bg));
            }
            // MLP down, swapped orientation: D[ch 16ctp+4lq+rg][tok lr]
            short8v hbf = (lq == 0) ? *(const short8v*)&hb[(16 * mt + lr) * 8] : zero8;
            const short* w2L = ws + WS_W2 + L * 512;
            f32x4 xf[4];
            #pragma unroll
            for (int ctp = 0; ctp < 4; ++ctp) {
                short8v a2 = (lq == 0) ? *(const short8v*)&w2L[(16 * ctp + lr) * 8] : zero8;
                f32x4 dacc = mfma32(a2, hbf, zero4);
                f32x4 b2v = *(const f32x4*)&b2[L * 64 + 16 * ctp + 4 * lq];
                #pragma unroll
                for (int rg = 0; rg < 4; ++rg) xf[ctp][rg] = xv[ctp][rg] + dacc[rg] + b2v[rg];
                if (iok) *(f32x4*)(xp + 16 * ctp + 4 * lq) = xf[ctp];
            }
            if (!LAST) {
                // LN1 of the next layer, straight from registers -> ybuf
                float t1, t2;
                stats_tree<4>(xf, t1, t2);
                t1 += __shfl_xor(t1, 16); t2 += __shfl_xor(t2, 16);
                t1 += __shfl_xor(t1, 32); t2 += __shfl_xor(t2, 32);
                const float mn = t1 * 0.015625f;
                const float rn = rsqrtf(t2 * 0.015625f - mn * mn + 1e-5f);
                const int r_ = i / P, c_ = i % P;
                const bool vok = iok && r_ >= 1 && r_ <= P - 2 && c_ >= 1 && c_ <= P - 2;
                if (vok) {
                    const int j = (r_ - 1) * (P - 2) + (c_ - 1);
                    unsigned* yw = (unsigned*)&ybuf[j * 72];
                    #pragma unroll
                    for (int ctp = 0; ctp < 4; ++ctp) {
                        f32x4 g  = *(const f32x4*)&ln1_g[(L + 1) * 64 + 16 * ctp + 4 * lq];
                        f32x4 bb = *(const f32x4*)&ln1_b[(L + 1) * 64 + 16 * ctp + 4 * lq];
                        yw[8 * ctp + 2 * lq]     = pk2((xf[ctp][0]-mn)*rn*g[0]+bb[0],
                                                       (xf[ctp][1]-mn)*rn*g[1]+bb[1]);
                        yw[8 * ctp + 2 * lq + 1] = pk2((xf[ctp][2]-mn)*rn*g[2]+bb[2],
                                                       (xf[ctp][3]-mn)*rn*g[3]+bb[3]);
                    }
                }
            }
        } else if (!LAST && wv == Mt) {
            // zero next layer's pad rows [Nn, 16*Mtn) in ybuf
            constexpr int Pn = P - 2, Nn = Pn * Pn, Mtn = (Nn + 15) / 16;
            constexpr int PadU = (16 * Mtn - Nn) * 36;
            unsigned* zb = (unsigned*)(ybuf + Nn * 72);
            for (int z = l; z < PadU; z += 64) zb[z] = 0;
        }
    }
    __syncthreads();

    if (LAST) {
        for (int idx = t; idx < 576; idx += NT) {
            const int d = idx / 9, rc = idx % 9;
            const int row = (rc / 3 + 3) * 9 + rc % 3 + 3;
            out[(size_t)b * 576 + idx] = xs[row * 68 + d];
        }
    }
}

__global__ __attribute__((amdgpu_flat_work_group_size(NT, NT), amdgpu_waves_per_eu(6, 6)))
void vit_kernel(
    const float* __restrict__ x_in, const short* __restrict__ ws,
    const float* __restrict__ b_qkv, const float* __restrict__ b_o,
    const float* __restrict__ ln1_g, const float* __restrict__ ln1_b,
    const float* __restrict__ ln2_g, const float* __restrict__ ln2_b,
    const float* __restrict__ b1,    const float* __restrict__ b2,
    float* __restrict__ out)
{
    __shared__ __align__(16) float xs[81 * 68];     // 22032 B
    __shared__ __align__(16) short ybuf[96 * 72];   // 13824 B  (LN1 in)
    __shared__ __align__(16) short qbf[96 * 72];    // 13824 B  (q, then attn-out)
    __shared__ __align__(16) short hb[96 * 8];      //  1536 B  (MLP hidden)

    const int b = blockIdx.x;
    const int t = threadIdx.x;

    const float* xin = x_in + (size_t)b * 5184;
    for (int q4 = t; q4 < 1296; q4 += NT) {
        const int i = q4 >> 4, dq = q4 & 15;
        *(f32x4*)&xs[i * 68 + dq * 4] = *(const f32x4*)&xin[i * 64 + dq * 4];
    }
    __syncthreads();

    layer_fn<81, 9, 0, true,  false>(xs, ybuf, qbf, hb, ws, b_qkv, b_o,
                                     ln1_g, ln1_b, ln2_g, ln2_b, b1, b2, out, b, t);
    layer_fn<49, 7, 1, false, false>(xs, ybuf, qbf, hb, ws, b_qkv, b_o,
                                     ln1_g, ln1_b, ln2_g, ln2_b, b1, b2, out, b, t);
    layer_fn<25, 5, 2, false, false>(xs, ybuf, qbf, hb, ws, b_qkv, b_o,
                                     ln1_g, ln1_b, ln2_g, ln2_b, b1, b2, out, b, t);
    layer_fn<9,  3, 3, false, true >(xs, ybuf, qbf, hb, ws, b_qkv, b_o,
                                     ln1_g, ln1_b, ln2_g, ln2_b, b1, b2, out, b, t);
}

extern "C" void kernel_launch(void* const* d_in, const int* in_sizes, int n_in,
                              void* d_out, int out_size, void* d_ws, size_t ws_size,
                              hipStream_t stream) {
    (void)n_in; (void)out_size; (void)ws_size;
    const float* x     = (const float*)d_in[0];
    const float* w_qkv = (const float*)d_in[1];
    const float* b_qkv = (const float*)d_in[2];
    const float* w_o   = (const float*)d_in[3];
    const float* b_o   = (const float*)d_in[4];
    const float* ln1_g = (const float*)d_in[5];
    const float* ln1_b = (const float*)d_in[6];
    const float* ln2_g = (const float*)d_in[7];
    const float* ln2_b = (const float*)d_in[8];
    const float* w1    = (const float*)d_in[9];
    const float* b1    = (const float*)d_in[10];
    const float* w2    = (const float*)d_in[11];
    const float* b2    = (const float*)d_in[12];
    short* ws = (short*)d_ws;

    prep_kernel<<<dim3((WS_TOT + 255) / 256), dim3(256), 0, stream>>>(w_qkv, w_o, w1, w2, ws);

    int B = in_sizes[0] / (81 * 64);
    vit_kernel<<<dim3(B), dim3(NT), 0, stream>>>(
        x, ws, b_qkv, b_o, ln1_g, ln1_b, ln2_g, ln2_b, b1, b2, (float*)d_out);
}

// Round 20
// 320.683 us; speedup vs baseline: 1.0698x; 1.0495x over previous
//
#include <hip/hip_runtime.h>
#include <hip/hip_bf16.h>
#include <math.h>

#define NT 512

typedef __attribute__((ext_vector_type(8))) short short8v;
typedef __attribute__((ext_vector_type(4))) short short4v;
typedef __attribute__((ext_vector_type(4))) float f32x4;
typedef __attribute__((ext_vector_type(2))) unsigned uint2v;
typedef __attribute__((ext_vector_type(4))) unsigned uint4v;

__device__ __forceinline__ unsigned short f2bf(float x) {   // prep kernel only
    unsigned u = __float_as_uint(x);
    unsigned r = ((u >> 16) & 1u) + 0x7FFFu;
    return (unsigned short)((u + r) >> 16);
}
__device__ __forceinline__ unsigned pk2(float a, float b) {
    __hip_bfloat162 h = __float22bfloat162_rn(make_float2(a, b));
    unsigned r;
    __builtin_memcpy(&r, &h, sizeof(r));
    return r;
}
__device__ __forceinline__ short bf1(float a) {
    __hip_bfloat16 h = __float2bfloat16(a);
    short r;
    __builtin_memcpy(&r, &h, sizeof(r));
    return r;
}
__device__ __forceinline__ float exp2fast(float x) {
#if __has_builtin(__builtin_amdgcn_exp2f)
    return __builtin_amdgcn_exp2f(x);
#else
    return exp2f(x);
#endif
}
__device__ __forceinline__ float rcpfast(float x) {
#if __has_builtin(__builtin_amdgcn_rcpf)
    return __builtin_amdgcn_rcpf(x);
#else
    return 1.0f / x;
#endif
}
// tanh-form gelu via exp2 + rcp (|err| vs erf-gelu ~3e-3, inside tolerance)
__device__ __forceinline__ float gelu_f(float x) {
    float x3 = x * x * x;
    float e = exp2fast(-2.3022079f * x - 0.1029432f * x3);
    return x * rcpfast(1.0f + e);
}
__device__ __forceinline__ f32x4 mfma32(short8v a, short8v b, f32x4 c) {
    return __builtin_amdgcn_mfma_f32_16x16x32_bf16(a, b, c, 0, 0, 0);
}
__device__ __forceinline__ f32x4 mfma16(short4v a, short4v b, f32x4 c) {
    return __builtin_amdgcn_mfma_f32_16x16x16bf16_1k(a, b, c, 0, 0, 0);
}

template<int M>
__device__ __forceinline__ void stats_tree(const f32x4* v, float& s1o, float& s2o) {
    float a[M], b[M];
    #pragma unroll
    for (int i = 0; i < M; ++i) {
        a[i] = (v[i][0] + v[i][1]) + (v[i][2] + v[i][3]);
        float q0 = v[i][0] * v[i][0], q1 = v[i][1] * v[i][1];
        float q2 = v[i][2] * v[i][2], q3 = v[i][3] * v[i][3];
        b[i] = (q0 + q1) + (q2 + q3);
    }
    #pragma unroll
    for (int s = 1; s < M; s *= 2)
        #pragma unroll
        for (int i = 0; i + s < M; i += 2 * s) { a[i] += a[i + s]; b[i] += b[i + s]; }
    s1o = a[0]; s2o = b[0];
}

// ws layout (bf16 shorts): wqkvT[L][192][64] @0 ; woT[L][64][64] @49152 ;
//                          w1T[L][16][64] @65536 (rows j>=8 zero) ; w2T[L][64][8] @69632
#define WS_WO 49152
#define WS_W1 65536
#define WS_W2 69632
#define WS_TOT 71680

__global__ __launch_bounds__(256) void prep_kernel(
    const float* __restrict__ w_qkv, const float* __restrict__ w_o,
    const float* __restrict__ w1, const float* __restrict__ w2,
    short* __restrict__ ws)
{
    int idx = blockIdx.x * 256 + threadIdx.x;
    if (idx < WS_WO) {
        int l = idx / 12288, r = idx % 12288, c = r >> 6, d = r & 63;
        ws[idx] = (short)f2bf(w_qkv[l * 12288 + d * 192 + c]);
    } else if (idx < WS_W1) {
        int k = idx - WS_WO; int l = k / 4096, r = k % 4096, c = r >> 6, d = r & 63;
        ws[idx] = (short)f2bf(w_o[l * 4096 + d * 64 + c]);
    } else if (idx < WS_W2) {
        int k = idx - WS_W1; int l = k / 1024, r = k % 1024, j = r >> 6, d = r & 63;
        ws[idx] = (j < 8) ? (short)f2bf(w1[l * 512 + d * 8 + j]) : (short)0;
    } else if (idx < WS_TOT) {
        int k = idx - WS_W2; int l = k / 512, r = k % 512, c = r >> 3, j = r & 7;
        ws[idx] = (short)f2bf(w2[l * 512 + j * 64 + c]);
    }
}

// LDS (51.2 KB): xs fp32 [81][68] (full 9x9 grid, ring-indexed);
// ybuf bf16 [96][72] = LN1 input; qbf bf16 [96][72] = attn-out; hb bf16 [96][8].
// Fully fused QKV+attention: wave h computes q (JIT per tile), k, v in registers
// from ybuf; 2 barriers/layer total.
template<int N, int P, int L, bool FIRST, bool LAST>
__device__ __forceinline__ void layer_fn(
    float* __restrict__ xs, short* __restrict__ ybuf, short* __restrict__ qbf,
    short* __restrict__ hb, const short* __restrict__ ws,
    const float* __restrict__ b_qkv, const float* __restrict__ b_o,
    const float* __restrict__ ln1_g, const float* __restrict__ ln1_b,
    const float* __restrict__ ln2_g, const float* __restrict__ ln2_b,
    const float* __restrict__ b1,    const float* __restrict__ b2,
    float* __restrict__ out, int b, int t)
{
    constexpr int Mt = (N + 15) / 16;
    constexpr float SCL2E = 0.51010905835f;   // (HEAD_DIM/HEADS)^-0.5 * log2(e)
    const int wv = t >> 6, l = t & 63, lr = l & 15, lq = l >> 4;
    short8v zero8 = {};
    f32x4 zero4 = {0.f, 0.f, 0.f, 0.f};

    // ---- phase A (first layer only): LN1 -> ybuf. 4 lanes per token ----
    if (FIRST) {
        if (t < 64 * Mt) {
            const int token = t >> 2, part = t & 3, d0 = part * 16;
            short* yrow = ybuf + token * 72 + d0;
            if (token < N) {
                const int row = (token / P + L) * 9 + token % P + L;
                const float* xr = xs + row * 68 + d0;
                f32x4 v[4];
                #pragma unroll
                for (int k = 0; k < 4; ++k) v[k] = *(const f32x4*)(xr + 4 * k);
                float s1, s2;
                stats_tree<4>(v, s1, s2);
                s1 += __shfl_xor(s1, 1); s2 += __shfl_xor(s2, 1);
                s1 += __shfl_xor(s1, 2); s2 += __shfl_xor(s2, 2);
                const float m = s1 * 0.015625f;
                const float r = rsqrtf(s2 * 0.015625f - m * m + 1e-5f);
                uint4v w0, w1v;
                #pragma unroll
                for (int k = 0; k < 4; ++k) {
                    f32x4 g  = *(const f32x4*)&ln1_g[L * 64 + d0 + 4 * k];
                    f32x4 bb = *(const f32x4*)&ln1_b[L * 64 + d0 + 4 * k];
                    unsigned p0 = pk2((v[k][0]-m)*r*g[0]+bb[0], (v[k][1]-m)*r*g[1]+bb[1]);
                    unsigned p1 = pk2((v[k][2]-m)*r*g[2]+bb[2], (v[k][3]-m)*r*g[3]+bb[3]);
                    if (k == 0) { w0.x = p0; w0.y = p1; }
                    else if (k == 1) { w0.z = p0; w0.w = p1; }
                    else if (k == 2) { w1v.x = p0; w1v.y = p1; }
                    else { w1v.z = p0; w1v.w = p1; }
                }
                *(uint4v*)yrow = w0;
                *(uint4v*)(yrow + 8) = w1v;
            } else {
                uint4v z = {};
                *(uint4v*)yrow = z;
                *(uint4v*)(yrow + 8) = z;
            }
        }
        __syncthreads();
    }

    // ---- phase C: fully fused qkv + attention. wave = head h.
    //      k/v in registers (combined pass, shared y loads); q computed JIT per
    //      query tile with the SAME srcl redistribution as k; attn-out written
    //      to qbf's own-head columns. ----
    {
        const int h = wv, a = h & 1, ct = h >> 1;
        const int srcl = lr + 32 * a + (l & 16);
        const short* wqL = ws + L * 12288;

        // hoisted weight fragments + biases for this wave's 16-channel group
        const short* wqr = &wqL[(16 * ct + lr) * 64 + lq * 8];
        short8v wq0 = *(const short8v*)wqr, wq1 = *(const short8v*)(wqr + 32);
        f32x4 qb = *(const f32x4*)&b_qkv[L * 192 + 16 * ct + lq * 4];
        const short* wkr = &wqL[(64 + 16 * ct + lr) * 64 + lq * 8];
        short8v wk0 = *(const short8v*)wkr, wk1 = *(const short8v*)(wkr + 32);
        f32x4 kb = *(const f32x4*)&b_qkv[L * 192 + 64 + 16 * ct + lq * 4];
        const short* wvr = &wqL[(128 + 16 * ct + lr) * 64 + lq * 8];
        short8v wv0 = *(const short8v*)wvr, wv1 = *(const short8v*)(wvr + 32);
        const float vbi = b_qkv[L * 192 + 128 + 16 * ct + lr];

        // combined k/v pass (one y-row load per tile)
        short4v vf[Mt];
        uint2v kf[Mt];
        #pragma unroll
        for (int mt = 0; mt < Mt; ++mt) {
            const short* yr = &ybuf[(16 * mt + lr) * 72 + lq * 8];
            short8v y0 = *(const short8v*)yr, y1 = *(const short8v*)(yr + 32);
            // v: unswapped GEMM -> D fragment == PV A-operand fragment
            f32x4 av = mfma32(y0, wv0, zero4);
            av = mfma32(y1, wv1, av);
            uint2v uv;
            uv.x = pk2(av[0] + vbi, av[1] + vbi);
            uv.y = pk2(av[2] + vbi, av[3] + vbi);
            vf[mt] = __builtin_bit_cast(short4v, uv);
            // k: swapped GEMM + redistribution (2 shfl) -> scores A fragment
            f32x4 ak = mfma32(wk0, y0, zero4);
            ak = mfma32(wk1, y1, ak);
            unsigned ka = pk2(ak[0] + kb[0], ak[1] + kb[1]);
            unsigned kc = pk2(ak[2] + kb[2], ak[3] + kb[3]);
            unsigned u0 = (unsigned)__shfl((int)ka, srcl);
            unsigned u1 = (unsigned)__shfl((int)kc, srcl);
            uint2v kv2; kv2.x = (l < 32) ? u0 : 0u; kv2.y = (l < 32) ? u1 : 0u;
            kf[mt] = kv2;
        }
        // scores + softmax + PV per query tile; q computed just-in-time
        for (int mt = 0; mt < Mt; ++mt) {
            const short* yr = &ybuf[(16 * mt + lr) * 72 + lq * 8];
            short8v y0 = *(const short8v*)yr, y1 = *(const short8v*)(yr + 32);
            f32x4 aq = mfma32(wq0, y0, zero4);
            aq = mfma32(wq1, y1, aq);
            unsigned qa = pk2((aq[0] + qb[0]) * SCL2E, (aq[1] + qb[1]) * SCL2E);
            unsigned qc = pk2((aq[2] + qb[2]) * SCL2E, (aq[3] + qb[3]) * SCL2E);
            unsigned uq0 = (unsigned)__shfl((int)qa, srcl);
            unsigned uq1 = (unsigned)__shfl((int)qc, srcl);
            uint2v qw; qw.x = (l < 32) ? uq0 : 0u; qw.y = (l < 32) ? uq1 : 0u;
            short4v qv = __builtin_bit_cast(short4v, qw);

            float psA = 0.f, psB = 0.f;
            f32x4 po0 = zero4, po1 = zero4;
            #pragma unroll
            for (int jt = 0; jt < Mt; ++jt) {
                f32x4 s = mfma16(__builtin_bit_cast(short4v, kf[jt]), qv, zero4);
                float e0 = exp2fast(s[0]), e1 = exp2fast(s[1]);
                float e2 = exp2fast(s[2]), e3 = exp2fast(s[3]);
                if (jt == Mt - 1) {   // only the last tile contains pad keys
                    const int j0 = 16 * jt + lq * 4;
                    e0 = (j0 + 0 < N) ? e0 : 0.f;
                    e1 = (j0 + 1 < N) ? e1 : 0.f;
                    e2 = (j0 + 2 < N) ? e2 : 0.f;
                    e3 = (j0 + 3 < N) ? e3 : 0.f;
                }
                psA += e0 + e1; psB += e2 + e3;
                uint2v pv; pv.x = pk2(e0, e1); pv.y = pk2(e2, e3);
                short4v bv = __builtin_bit_cast(short4v, pv);
                if (jt & 1) po1 = mfma16(vf[jt], bv, po1);
                else        po0 = mfma16(vf[jt], bv, po0);
            }
            float psum = psA + psB;
            float den = psum + __shfl_xor(psum, 16);
            den += __shfl_xor(den, 32);
            const float dinv = rcpfast(den);
            if ((lq >> 1) == a) {
                const int i = 16 * mt + lr;
                if (i < N) {
                    unsigned q0 = pk2((po0[0] + po1[0]) * dinv, (po0[1] + po1[1]) * dinv);
                    unsigned q1 = pk2((po0[2] + po1[2]) * dinv, (po0[3] + po1[3]) * dinv);
                    unsigned* dst = (unsigned*)&qbf[i * 72 + 8 * h + (lq & 1) * 4];
                    dst[0] = q0; dst[1] = q1;
                }
            }
        }
    }
    __syncthreads();

    // ---- phase D (fused, wave-local): w_o + residual + LN2 + MLP + residual
    //      + LN1-of-next-layer written into ybuf. ----
    {
        if (wv < Mt) {
            const int mt = wv;
            const int i = 16 * mt + lr;          // token (this layer)
            const bool iok = (i < N);
            const int xrow = iok ? (i / P + L) * 9 + (i % P) + L : 0;
            float* xp = xs + xrow * 68;
            const short* yr = &qbf[i * 72 + lq * 8];   // attn-out
            short8v y0 = *(const short8v*)yr;
            short8v y1 = *(const short8v*)(yr + 32);
            const short* woL = ws + WS_WO + L * 4096;
            f32x4 xv[4];
            #pragma unroll
            for (int ctp = 0; ctp < 4; ++ctp) {
                const short* wr = &woL[(16 * ctp + lr) * 64 + lq * 8];
                f32x4 acc = mfma32(*(const short8v*)wr, y0, zero4);
                acc = mfma32(*(const short8v*)(wr + 32), y1, acc);
                f32x4 bo = *(const f32x4*)&b_o[L * 64 + 16 * ctp + 4 * lq];
                f32x4 xc = zero4;
                if (iok) xc = *(const f32x4*)(xp + 16 * ctp + 4 * lq);
                #pragma unroll
                for (int rg = 0; rg < 4; ++rg) xc[rg] += acc[rg] + bo[rg];
                xv[ctp] = xc;
            }
            float s1, s2;
            stats_tree<4>(xv, s1, s2);
            s1 += __shfl_xor(s1, 16); s2 += __shfl_xor(s2, 16);
            s1 += __shfl_xor(s1, 32); s2 += __shfl_xor(s2, 32);
            const float m = s1 * 0.015625f;
            const float r = rsqrtf(s2 * 0.015625f - m * m + 1e-5f);
            unsigned* abw = (unsigned*)&qbf[i * 72];
            #pragma unroll
            for (int ctp = 0; ctp < 4; ++ctp) {
                f32x4 g  = *(const f32x4*)&ln2_g[L * 64 + 16 * ctp + 4 * lq];
                f32x4 bb = *(const f32x4*)&ln2_b[L * 64 + 16 * ctp + 4 * lq];
                abw[8 * ctp + 2 * lq]     = pk2((xv[ctp][0]-m)*r*g[0]+bb[0],
                                                (xv[ctp][1]-m)*r*g[1]+bb[1]);
                abw[8 * ctp + 2 * lq + 1] = pk2((xv[ctp][2]-m)*r*g[2]+bb[2],
                                                (xv[ctp][3]-m)*r*g[3]+bb[3]);
            }
            // MLP up (same-wave LDS round-trip, matched unsigned types)
            uint4v ua0 = *(const uint4v*)(abw + 4 * lq);
            uint4v ua1 = *(const uint4v*)(abw + 16 + 4 * lq);
            const short* w1L = ws + WS_W1 + L * 1024;
            short8v a10 = __builtin_bit_cast(short8v, ua0);
            short8v a11 = __builtin_bit_cast(short8v, ua1);
            short8v b10 = *(const short8v*)&w1L[lr * 64 + lq * 8];
            short8v b11 = *(const short8v*)&w1L[lr * 64 + lq * 8 + 32];
            f32x4 hA = mfma32(a10, b10, zero4);
            hA = mfma32(a11, b11, hA);
            if (lr < 8) {
                const float bg = b1[L * 8 + lr];
                #pragma unroll
                for (int rg = 0; rg < 4; ++rg)
                    hb[(16 * mt + 4 * lq + rg) * 8 + lr] = bf1(gelu_f(hA[rg] + bg));
            }
            // MLP down, swapped orientation: D[ch 16ctp+4lq+rg][tok lr]
            short8v hbf = (lq == 0) ? *(const short8v*)&hb[(16 * mt + lr) * 8] : zero8;
            const short* w2L = ws + WS_W2 + L * 512;
            f32x4 xf[4];
            #pragma unroll
            for (int ctp = 0; ctp < 4; ++ctp) {
                short8v a2 = (lq == 0) ? *(const short8v*)&w2L[(16 * ctp + lr) * 8] : zero8;
                f32x4 dacc = mfma32(a2, hbf, zero4);
                f32x4 b2v = *(const f32x4*)&b2[L * 64 + 16 * ctp + 4 * lq];
                #pragma unroll
                for (int rg = 0; rg < 4; ++rg) xf[ctp][rg] = xv[ctp][rg] + dacc[rg] + b2v[rg];
                if (iok) *(f32x4*)(xp + 16 * ctp + 4 * lq) = xf[ctp];
            }
            if (!LAST) {
                // LN1 of the next layer, straight from registers -> ybuf
                float t1, t2;
                stats_tree<4>(xf, t1, t2);
                t1 += __shfl_xor(t1, 16); t2 += __shfl_xor(t2, 16);
                t1 += __shfl_xor(t1, 32); t2 += __shfl_xor(t2, 32);
                const float mn = t1 * 0.015625f;
                const float rn = rsqrtf(t2 * 0.015625f - mn * mn + 1e-5f);
                const int r_ = i / P, c_ = i % P;
                const bool vok = iok && r_ >= 1 && r_ <= P - 2 && c_ >= 1 && c_ <= P - 2;
                if (vok) {
                    const int j = (r_ - 1) * (P - 2) + (c_ - 1);
                    unsigned* yw = (unsigned*)&ybuf[j * 72];
                    #pragma unroll
                    for (int ctp = 0; ctp < 4; ++ctp) {
                        f32x4 g  = *(const f32x4*)&ln1_g[(L + 1) * 64 + 16 * ctp + 4 * lq];
                        f32x4 bb = *(const f32x4*)&ln1_b[(L + 1) * 64 + 16 * ctp + 4 * lq];
                        yw[8 * ctp + 2 * lq]     = pk2((xf[ctp][0]-mn)*rn*g[0]+bb[0],
                                                       (xf[ctp][1]-mn)*rn*g[1]+bb[1]);
                        yw[8 * ctp + 2 * lq + 1] = pk2((xf[ctp][2]-mn)*rn*g[2]+bb[2],
                                                       (xf[ctp][3]-mn)*rn*g[3]+bb[3]);
                    }
                }
            }
        } else if (!LAST && wv == Mt) {
            // zero next layer's pad rows [Nn, 16*Mtn) in ybuf
            constexpr int Pn = P - 2, Nn = Pn * Pn, Mtn = (Nn + 15) / 16;
            constexpr int PadU = (16 * Mtn - Nn) * 36;
            unsigned* zb = (unsigned*)(ybuf + Nn * 72);
            for (int z = l; z < PadU; z += 64) zb[z] = 0;
        }
    }
    __syncthreads();

    if (LAST) {
        for (int idx = t; idx < 576; idx += NT) {
            const int d = idx / 9, rc = idx % 9;
            const int row = (rc / 3 + 3) * 9 + rc % 3 + 3;
            out[(size_t)b * 576 + idx] = xs[row * 68 + d];
        }
    }
}

__global__ __launch_bounds__(NT, 4) void vit_kernel(
    const float* __restrict__ x_in, const short* __restrict__ ws,
    const float* __restrict__ b_qkv, const float* __restrict__ b_o,
    const float* __restrict__ ln1_g, const float* __restrict__ ln1_b,
    const float* __restrict__ ln2_g, const float* __restrict__ ln2_b,
    const float* __restrict__ b1,    const float* __restrict__ b2,
    float* __restrict__ out)
{
    __shared__ __align__(16) float xs[81 * 68];     // 22032 B
    __shared__ __align__(16) short ybuf[96 * 72];   // 13824 B  (LN1 in)
    __shared__ __align__(16) short qbf[96 * 72];    // 13824 B  (attn-out)
    __shared__ __align__(16) short hb[96 * 8];      //  1536 B  (MLP hidden)

    const int b = blockIdx.x;
    const int t = threadIdx.x;

    // zero qbf once: layer-0 pad rows are read in phase D (keep deterministic)
    for (int idx = t; idx < 96 * 72; idx += NT) qbf[idx] = 0;

    const float* xin = x_in + (size_t)b * 5184;
    for (int q4 = t; q4 < 1296; q4 += NT) {
        const int i = q4 >> 4, dq = q4 & 15;
        *(f32x4*)&xs[i * 68 + dq * 4] = *(const f32x4*)&xin[i * 64 + dq * 4];
    }
    __syncthreads();

    layer_fn<81, 9, 0, true,  false>(xs, ybuf, qbf, hb, ws, b_qkv, b_o,
                                     ln1_g, ln1_b, ln2_g, ln2_b, b1, b2, out, b, t);
    layer_fn<49, 7, 1, false, false>(xs, ybuf, qbf, hb, ws, b_qkv, b_o,
                                     ln1_g, ln1_b, ln2_g, ln2_b, b1, b2, out, b, t);
    layer_fn<25, 5, 2, false, false>(xs, ybuf, qbf, hb, ws, b_qkv, b_o,
                                     ln1_g, ln1_b, ln2_g, ln2_b, b1, b2, out, b, t);
    layer_fn<9,  3, 3, false, true >(xs, ybuf, qbf, hb, ws, b_qkv, b_o,
                                     ln1_g, ln1_b, ln2_g, ln2_b, b1, b2, out, b, t);
}

extern "C" void kernel_launch(void* const* d_in, const int* in_sizes, int n_in,
                              void* d_out, int out_size, void* d_ws, size_t ws_size,
                              hipStream_t stream) {
    (void)n_in; (void)out_size; (void)ws_size;
    const float* x     = (const float*)d_in[0];
    const float* w_qkv = (const float*)d_in[1];
    const float* b_qkv = (const float*)d_in[2];
    const float* w_o   = (const float*)d_in[3];
    const float* b_o   = (const float*)d_in[4];
    const float* ln1_g = (const float*)d_in[5];
    const float* ln1_b = (const float*)d_in[6];
    const float* ln2_g = (const float*)d_in[7];
    const float* ln2_b = (const float*)d_in[8];
    const float* w1    = (const float*)d_in[9];
    const float* b1    = (const float*)d_in[10];
    const float* w2    = (const float*)d_in[11];
    const float* b2    = (const float*)d_in[12];
    short* ws = (short*)d_ws;

    prep_kernel<<<dim3((WS_TOT + 255) / 256), dim3(256), 0, stream>>>(w_qkv, w_o, w1, w2, ws);

    int B = in_sizes[0] / (81 * 64);
    vit_kernel<<<dim3(B), dim3(NT), 0, stream>>>(
        x, ws, b_qkv, b_o, ln1_g, ln1_b, ln2_g, ln2_b, b1, b2, (float*)d_out);
}